// Round 17
// baseline (644.280 us; speedup 1.0000x reference)
//
#include <hip/hip_runtime.h>
#include <math.h>

#define H 64
#define VOCABN 64
#define LSEQ 2048
#define LN_EPS 1e-5f

// ---------- generic DPP add helper ----------
template <int CTRL>
__device__ __forceinline__ float dpp_add(float x) {
  return x + __int_as_float(__builtin_amdgcn_update_dpp(
      0, __float_as_int(x), CTRL, 0xF, 0xF, true));
}

// all-lane sum with broadcast result (tables / readout only)
__device__ __forceinline__ float wave_allsum(float x) {
  x = dpp_add<0xB1>(x);   // quad_perm [1,0,3,2]
  x = dpp_add<0x4E>(x);   // quad_perm [2,3,0,1]
  x = dpp_add<0x141>(x);  // row_half_mirror
  x = dpp_add<0x140>(x);  // row_mirror
  x += __shfl_xor(x, 16, 64);
  x += __shfl_xor(x, 32, 64);
  return x;
}

__device__ __forceinline__ float rdlf(float v, int lane) {
  return __int_as_float(__builtin_amdgcn_readlane(__float_as_int(v), lane));
}

// 16-component bracketed sum of squares, group base B (compile-time).
// Bracketing identical to round 16's norm2_tree (p/q/o/h structure), which is
// the register-space replica of the DPP row_shr/row_bcast lane-63 chain.
// Minimal live temps (~6) to keep register pressure under the 256-VGPR file.
template <int B>
__device__ __forceinline__ float grp16_nrm(const float* RT) {
  float q0 = (RT[B + 3] * RT[B + 3] + RT[B + 2] * RT[B + 2]) +
             (RT[B + 1] * RT[B + 1] + RT[B + 0] * RT[B + 0]);
  float q1 = (RT[B + 7] * RT[B + 7] + RT[B + 6] * RT[B + 6]) +
             (RT[B + 5] * RT[B + 5] + RT[B + 4] * RT[B + 4]);
  float o0 = q1 + q0;
  float q2 = (RT[B + 11] * RT[B + 11] + RT[B + 10] * RT[B + 10]) +
             (RT[B + 9] * RT[B + 9] + RT[B + 8] * RT[B + 8]);
  float q3 = (RT[B + 15] * RT[B + 15] + RT[B + 14] * RT[B + 14]) +
             (RT[B + 13] * RT[B + 13] + RT[B + 12] * RT[B + 12]);
  float o1 = q3 + q2;
  return o1 + o0;
}

// full 64-component norm^2 with the fixed bracket (== DPP lane63 value, bitwise)
__device__ __forceinline__ float norm2_tree(const float* RT) {
  float h0 = grp16_nrm<0>(RT);
  float h1 = grp16_nrm<16>(RT);
  float h2 = grp16_nrm<32>(RT);
  float h3 = grp16_nrm<48>(RT);
  return (h3 + h2) + (h1 + h0);
}

// ---------------- Kernel A: per-token tables (verbatim rounds 7-16, passed) ----------------
__global__ __launch_bounds__(64) void tables_kernel(
    const float* __restrict__ embed, const float* __restrict__ W1, const float* __restrict__ b1,
    const float* __restrict__ W2, const float* __restrict__ b2,
    const float* __restrict__ ln_g, const float* __restrict__ ln_b,
    const float* __restrict__ Wk, const float* __restrict__ Wv,
    float* __restrict__ Htab, float* __restrict__ Ktab, float* __restrict__ Vtab,
    float* __restrict__ nvtab)
{
  __shared__ float hs[H];
  __shared__ float ff1[2 * H];
  __shared__ float lns[H];
  const int c = blockIdx.x;
  const int i = threadIdx.x;

  float e = embed[c * H + i];
  hs[i] = e;
  __syncthreads();

  float r1 = b1[i], r2 = b1[i + H];
  for (int j = 0; j < H; ++j) {
    float hj = hs[j];
    r1 = fmaf(W1[i * H + j], hj, r1);
    r2 = fmaf(W1[(i + H) * H + j], hj, r2);
  }
  ff1[i]     = fmaxf(r1, 0.f);
  ff1[i + H] = fmaxf(r2, 0.f);
  __syncthreads();

  float o = b2[i];
  for (int m = 0; m < 2 * H; ++m) o = fmaf(W2[i * 2 * H + m], ff1[m], o);
  float y = e + o;

  float mu  = wave_allsum(y) * (1.f / H);
  float d   = y - mu;
  float var = wave_allsum(d * d) * (1.f / H);
  float ln  = d * (1.f / sqrtf(var + LN_EPS)) * ln_g[i] + ln_b[i];
  lns[i] = ln;
  __syncthreads();
  Htab[c * H + i] = ln;

  float k = 0.f, v = 0.f;
  for (int j = 0; j < H; ++j) {
    float lj = lns[j];
    k = fmaf(Wk[i * H + j], lj, k);
    v = fmaf(Wv[i * H + j], lj, v);
  }
  float nk = sqrtf(wave_allsum(k * k));
  Ktab[c * H + i] = k / fmaxf(nk, 1e-12f);
  Vtab[c * H + i] = v;
  float nv = sqrtf(wave_allsum(v * v));
  if (i == 0) nvtab[c] = 0.4f * nv;   // gate threshold, sqrt domain
}

// ---------------- Kernel B: single-wave register-resident scan (low-pressure) ----------------
// One WAVE per batch element. RT[i] (reg i, lane c) = residual comp i of token c;
// Mg[i] (reg i, lane j) = M[i][j]; nrm2v (lane c) = ||R[c]||^2 tree-bracketed.
// Reject: 2 readlane + sqrt + scalar branch (no LDS, no barriers). Accept: fused
// per-16-group {64 readlane + 128 FMA + bracketed norm} — minimal temps so
// RT/Mg stay in arch VGPRs (round 16's AGPR-shuffle overhead removed).
// All arithmetic bitwise identical to rounds 10-16 (passed).
__global__ __launch_bounds__(64, 1) void scan_kernel(
    const int* __restrict__ x, const float* __restrict__ Htab,
    const float* __restrict__ Ktab, const float* __restrict__ Vtab,
    const float* __restrict__ nvtab,
    const float* __restrict__ Wq, const float* __restrict__ Wr,
    const float* __restrict__ alpha, const float* __restrict__ Wout,
    const float* __restrict__ bout, float* __restrict__ out)
{
  __shared__ float4 Kl4[VOCABN * H / 4];   // khat [c][j]  16KB
  __shared__ float  Gl[VOCABN * H];        // Gram [c][cc] 16KB
  __shared__ float4 Vp4[VOCABN * 17];      // V staged padded [c][68]
  __shared__ int    xl[LSEQ];              // 8KB
  __shared__ float  Mt[VOCABN * 65];       // M^T padded: Mt[j*65+i] = M[i][j]
  __shared__ float  hbuf[H];
  __shared__ float  qbuf[H];
  __shared__ float  mbuf[H];
  float* Kl = (float*)Kl4;
  float* Vp = (float*)Vp4;

  const int b    = blockIdx.x;
  const int lane = threadIdx.x;

  // ---- stage K (linear), V (pad-68), x ----
  {
    const float4* Kg = (const float4*)Ktab;
    const float4* Vg = (const float4*)Vtab;
    for (int q = lane; q < VOCABN * H / 4; q += 64) {
      Kl4[q] = Kg[q];
      Vp4[(q >> 4) * 17 + (q & 15)] = Vg[q];
    }
    const int4* xg = (const int4*)(x + b * LSEQ);
    int4* xl4 = (int4*)xl;
    for (int q = lane; q < LSEQ / 4; q += 64) xl4[q] = xg[q];
  }
  float thrv = nvtab[lane];
  __syncthreads();

  // ---- Gram in LDS (same fmaf structure as rounds 10-16 -> bitwise same G) ----
  {
    float4 kr[16];
#pragma unroll
    for (int q2 = 0; q2 < 16; ++q2) kr[q2] = Kl4[lane * 16 + q2];
    for (int a = 0; a < VOCABN; ++a) {
      const float4* kp2 = (const float4*)(Kl + a * H);
      float a0 = 0.f, a1 = 0.f, a2 = 0.f, a3 = 0.f;
#pragma unroll
      for (int q2 = 0; q2 < 16; ++q2) {
        float4 kq = kp2[q2];
        a0 = fmaf(kr[q2].x, kq.x, a0);
        a1 = fmaf(kr[q2].y, kq.y, a1);
        a2 = fmaf(kr[q2].z, kq.z, a2);
        a3 = fmaf(kr[q2].w, kq.w, a3);
      }
      Gl[a * H + lane] = (a0 + a1) + (a2 + a3);
    }
  }
  __syncthreads();

  // ---- residuals + M in registers (transposed) ----
  float RT[64], Mg[64];
#pragma unroll
  for (int i = 0; i < 64; ++i) {
    RT[i] = Vp[lane * 68 + i];   // RT[i][lane=c] = v_c[i]  (M = 0)
    Mg[i] = 0.f;
  }
  float nrm2v = norm2_tree(RT);

  // ---- depth-3 prefetch pipeline over the static token stream ----
  int c0 = __builtin_amdgcn_readfirstlane(xl[0]);
  int c1 = __builtin_amdgcn_readfirstlane(xl[1]);
  int c2 = __builtin_amdgcn_readfirstlane(xl[2]);
  float gv0 = Gl[c0 * H + lane], kv0 = Kl[c0 * H + lane];
  float gv1 = Gl[c1 * H + lane], kv1 = Kl[c1 * H + lane];
  float gv2 = Gl[c2 * H + lane], kv2 = Kl[c2 * H + lane];

  for (int t = 0; t < LSEQ; ++t) {
    const int i3 = (t + 3 < LSEQ) ? t + 3 : LSEQ - 1;
    const int c3 = __builtin_amdgcn_readfirstlane(xl[i3]);
    float gv3 = Gl[c3 * H + lane];
    float kv3 = Kl[c3 * H + lane];

    float nd2 = rdlf(nrm2v, c0);
    float thc = rdlf(thrv, c0);

    if (sqrtf(nd2) > thc) {               // uniform scalar branch
      // fused update + norm per 16-group: minimal live temps
      float h0, h1, h2, h3;
#pragma unroll
      for (int g2 = 0; g2 < 4; ++g2) {
#pragma unroll
        for (int i = 0; i < 16; ++i) {
          const int ii = g2 * 16 + i;
          float s = rdlf(RT[ii], c0);     // delta[ii]
          RT[ii] = fmaf(-s, gv0, RT[ii]); // == fmaf(-g, delta, R) bitwise
          Mg[ii] = fmaf(s, kv0, Mg[ii]);  // == fmaf(delta, k, M) bitwise
        }
        float hg = (g2 == 0) ? grp16_nrm<0>(RT)
                 : (g2 == 1) ? grp16_nrm<16>(RT)
                 : (g2 == 2) ? grp16_nrm<32>(RT)
                             : grp16_nrm<48>(RT);
        if      (g2 == 0) h0 = hg;
        else if (g2 == 1) h1 = hg;
        else if (g2 == 2) h2 = hg;
        else              h3 = hg;
      }
      nrm2v = (h3 + h2) + (h1 + h0);      // bitwise == DPP lane63 norms
    }

    c0 = c1; c1 = c2; c2 = c3;
    gv0 = gv1; gv1 = gv2; gv2 = gv3;
    kv0 = kv1; kv1 = kv2; kv2 = kv3;
  }

  // ---- M^T into padded LDS (conflict-free: stride 65) ----
#pragma unroll
  for (int i = 0; i < 64; ++i) Mt[lane * 65 + i] = Mg[i];
  __syncthreads();

  // ---------------- fused readout (arithmetic identical to rounds 12-16) ----------------
  const int clast = __builtin_amdgcn_readfirstlane(xl[LSEQ - 1]);
  hbuf[lane] = Htab[clast * H + lane];
  __syncthreads();

  float qi = 0.f;
  for (int j = 0; j < H; ++j) qi = fmaf(Wq[lane * H + j], hbuf[j], qi);
  qbuf[lane] = qi;
  __syncthreads();

  float qri = 0.f;
  for (int j = 0; j < H; ++j) qri = fmaf(Wr[lane * H + j], qbuf[j], qri);

  // slot norms^2 (slot s = column s of M): n2[lane] = sum_i M[i][lane]^2
  float n2 = 0.f;
#pragma unroll
  for (int i2 = 0; i2 < 64; ++i2) n2 = fmaf(Mg[i2], Mg[i2], n2);

  // top-8 slots by norm (ties -> smaller index)
  const int KS = 8;
  int idxs[KS];
  float nloc = n2;
#pragma unroll
  for (int k = 0; k < KS; ++k) {
    float v = nloc; int idx = lane;
#pragma unroll
    for (int s = 1; s < 64; s <<= 1) {
      float ov = __shfl_xor(v, s, 64);
      int   oi = __shfl_xor(idx, s, 64);
      if (ov > v || (ov == v && oi < idx)) { v = ov; idx = oi; }
    }
    idxs[k] = idx;
    if (lane == idx) nloc = -1.f;
  }

  float sel[KS], lg[KS];
#pragma unroll
  for (int k = 0; k < KS; ++k) {
    float s = Mt[idxs[k] * 65 + lane];    // M_T[idx][lane]
    sel[k] = s;
    lg[k] = wave_allsum(s * qri) * 0.125f;   // / sqrt(64)
  }
  float lmax = lg[0];
#pragma unroll
  for (int k = 1; k < KS; ++k) lmax = fmaxf(lmax, lg[k]);
  float esum = 0.f, retro = 0.f;
#pragma unroll
  for (int k = 0; k < KS; ++k) {
    float e = expf(lg[k] - lmax);
    esum += e;
    retro = fmaf(e, sel[k], retro);
  }
  retro /= esum;

  // m_ctx = M q : mc[lane=i] = sum_j M_T[j][lane] q[j]
  float mc = 0.f;
  for (int j = 0; j < H; ++j) mc = fmaf(Mt[j * 65 + lane], qbuf[j], mc);

  float a = 1.f / (1.f + expf(-alpha[0]));
  float mixed = fmaxf(fmaf(a, retro, (1.f - a) * mc), 0.f);
  mbuf[lane] = mixed;
  __syncthreads();

  float oo = bout[lane];
  for (int i2 = 0; i2 < H; ++i2) oo = fmaf(Wout[lane * H + i2], mbuf[i2], oo);
  out[b * VOCABN + lane] = oo;
}

extern "C" void kernel_launch(void* const* d_in, const int* in_sizes, int n_in,
                              void* d_out, int out_size, void* d_ws, size_t ws_size,
                              hipStream_t stream) {
  const int*   x     = (const int*)d_in[0];
  const float* embed = (const float*)d_in[1];
  const float* W1    = (const float*)d_in[2];
  const float* b1    = (const float*)d_in[3];
  const float* W2    = (const float*)d_in[4];
  const float* b2    = (const float*)d_in[5];
  const float* ln_g  = (const float*)d_in[6];
  const float* ln_b  = (const float*)d_in[7];
  const float* Wk    = (const float*)d_in[8];
  const float* Wv    = (const float*)d_in[9];
  const float* Wq    = (const float*)d_in[10];
  const float* Wr    = (const float*)d_in[11];
  const float* alpha = (const float*)d_in[12];
  const float* Wout  = (const float*)d_in[13];
  const float* bout  = (const float*)d_in[14];
  float* out = (float*)d_out;

  const int B = in_sizes[0] / LSEQ;

  float* ws    = (float*)d_ws;
  float* Htab  = ws;          // 4096
  float* Ktab  = ws + 4096;   // 4096
  float* Vtab  = ws + 8192;   // 4096
  float* nvtab = ws + 12288;  // 64

  tables_kernel<<<VOCABN, 64, 0, stream>>>(embed, W1, b1, W2, b2, ln_g, ln_b,
                                           Wk, Wv, Htab, Ktab, Vtab, nvtab);
  scan_kernel<<<B, 64, 0, stream>>>(x, Htab, Ktab, Vtab, nvtab,
                                    Wq, Wr, alpha, Wout, bout, out);
}